// Round 1
// baseline (704.521 us; speedup 1.0000x reference)
//
#include <hip/hip_runtime.h>

typedef unsigned int uint;
typedef unsigned short ushort_t;

// Problem constants
#define CN 32          // channels
#define HH 64
#define WW 64
#define HW 4096        // H*W
#define KDIM 288       // C*9
#define PDIM 8192      // N*HW
#define NB 2           // batch

static __device__ __forceinline__ ushort_t f2bf(float f) {
    uint u = __float_as_uint(f);
    uint r = (u + 0x7fffu + ((u >> 16) & 1u)) >> 16;
    return (ushort_t)r;
}

// ---------------- conv1 + relu: x (N,32,64,64) -> h ----------------
__global__ __launch_bounds__(256) void conv1_relu(
    const float* __restrict__ x, const float* __restrict__ w1,
    float* __restrict__ hout)
{
    int idx = blockIdx.x * 256 + threadIdx.x;   // N*C*HW = 262144 total
    int w  = idx & 63;
    int hh = (idx >> 6) & 63;
    int c  = (idx >> 12) & 31;
    int n  = idx >> 17;
    const float* wp = w1 + c * KDIM;
    float acc = 0.f;
    for (int ci = 0; ci < CN; ci++) {
        const float* xp = x + (((size_t)n * CN + ci) << 12);
        #pragma unroll
        for (int kh = 0; kh < 3; kh++) {
            int y = hh + kh - 1;
            if ((unsigned)y >= 64u) continue;
            #pragma unroll
            for (int kw = 0; kw < 3; kw++) {
                int xw = w + kw - 1;
                if ((unsigned)xw >= 64u) continue;
                acc = fmaf(xp[(y << 6) + xw], wp[ci * 9 + kh * 3 + kw], acc);
            }
        }
    }
    hout[idx] = fmaxf(acc, 0.f);
}

// ---------------- im2col of h: Bm[k=ci*9+kk][p=n*4096+sp] ----------------
__global__ __launch_bounds__(256) void im2col_k(
    const float* __restrict__ h, float* __restrict__ Bm)
{
    int idx = blockIdx.x * 256 + threadIdx.x;   // KDIM*PDIM
    int p = idx & (PDIM - 1);
    int k = idx >> 13;
    int n  = p >> 12;
    int sp = p & 4095;
    int hh = sp >> 6;
    int w  = sp & 63;
    int ci = k / 9;
    int kk = k - ci * 9;
    int kh = kk / 3;
    int kw = kk - kh * 3;
    int y  = hh + kh - 1;
    int xw = w + kw - 1;
    float v = 0.f;
    if ((unsigned)y < 64u && (unsigned)xw < 64u)
        v = h[(((size_t)n * CN + ci) << 12) + (y << 6) + xw];
    Bm[idx] = v;
}

// ---------------- GEMM (fp32) + tanh + bf16 store ----------------
// A: [Mc][288] (already offset by ch0), Bm: [288][8192]
// Wb[(n*Mc + m)*4096 + sp] = bf16(tanh(sum_k A[m][k]*Bm[k][p])), p = n*4096+sp
__global__ __launch_bounds__(256) void gemm_tanh(
    const float* __restrict__ A, const float* __restrict__ Bm,
    ushort_t* __restrict__ Wb, int Mc)
{
    __shared__ float As[16][72];
    __shared__ float Bs[16][72];
    int tid = threadIdx.x;
    int p0 = blockIdx.x * 64;
    int m0 = blockIdx.y * 64;
    int tx = tid & 15;       // m direction
    int ty = tid >> 4;       // p direction
    float acc[4][4] = {};

    for (int k0 = 0; k0 < KDIM; k0 += 16) {
        // A tile: 64 rows x 16 k  (lanes: kk fast -> 64B coalesced)
        {
            int kk = tid & 15;
            int mb = tid >> 4;
            #pragma unroll
            for (int ph = 0; ph < 4; ph++) {
                int m = mb + ph * 16;
                As[kk][m] = A[(size_t)(m0 + m) * KDIM + k0 + kk];
            }
            int pc = tid & 63;
            int kr = tid >> 6;
            #pragma unroll
            for (int ph = 0; ph < 4; ph++) {
                int row = kr + ph * 4;
                Bs[row][pc] = Bm[(size_t)(k0 + row) * PDIM + p0 + pc];
            }
        }
        __syncthreads();
        #pragma unroll
        for (int kk = 0; kk < 16; kk++) {
            float4 av = *(const float4*)&As[kk][tx * 4];
            float4 bv = *(const float4*)&Bs[kk][ty * 4];
            acc[0][0] = fmaf(av.x, bv.x, acc[0][0]);
            acc[0][1] = fmaf(av.x, bv.y, acc[0][1]);
            acc[0][2] = fmaf(av.x, bv.z, acc[0][2]);
            acc[0][3] = fmaf(av.x, bv.w, acc[0][3]);
            acc[1][0] = fmaf(av.y, bv.x, acc[1][0]);
            acc[1][1] = fmaf(av.y, bv.y, acc[1][1]);
            acc[1][2] = fmaf(av.y, bv.z, acc[1][2]);
            acc[1][3] = fmaf(av.y, bv.w, acc[1][3]);
            acc[2][0] = fmaf(av.z, bv.x, acc[2][0]);
            acc[2][1] = fmaf(av.z, bv.y, acc[2][1]);
            acc[2][2] = fmaf(av.z, bv.z, acc[2][2]);
            acc[2][3] = fmaf(av.z, bv.w, acc[2][3]);
            acc[3][0] = fmaf(av.w, bv.x, acc[3][0]);
            acc[3][1] = fmaf(av.w, bv.y, acc[3][1]);
            acc[3][2] = fmaf(av.w, bv.z, acc[3][2]);
            acc[3][3] = fmaf(av.w, bv.w, acc[3][3]);
        }
        __syncthreads();
    }

    // epilogue: tanh + bf16 pack, 8B stores
    int n   = p0 >> 12;           // whole tile same n (64 | 4096)
    int sp0 = (p0 & 4095) + ty * 4;
    #pragma unroll
    for (int i = 0; i < 4; i++) {
        int m = m0 + tx * 4 + i;
        size_t base = ((size_t)(n * Mc + m) << 12) + sp0;
        alignas(8) ushort_t t4[4];
        #pragma unroll
        for (int j = 0; j < 4; j++)
            t4[j] = f2bf(tanhf(acc[i][j]));
        *(uint2*)&Wb[base] = *(const uint2*)t4;
    }
}

// ---------------- apply: out[n,co,h,w] = sum_{ci,kk} W * x ----------------
// weight value for (co,ci,h,w,kk) is contiguous in Wb:
//   Wb[(n*Mc + ((co-co0)*32+ci)*9)*4096 + h*576 + w*9 + kk]
__global__ __launch_bounds__(256) void apply_kernel(
    const float* __restrict__ x, const ushort_t* __restrict__ Wb,
    float* __restrict__ out, int co0, int Mc)
{
    __shared__ uint sW[1152];      // 4 rows * 576 bf16 = 2304 bf16
    int tid = threadIdx.x;
    int ly  = blockIdx.y;          // local co
    int co  = co0 + ly;
    int n   = blockIdx.z;
    int h0  = blockIdx.x * 4;
    int r = tid >> 6;
    int w = tid & 63;
    int h = h0 + r;
    float acc = 0.f;

    for (int ci = 0; ci < CN; ci++) {
        __syncthreads();
        size_t base = (((size_t)(n * Mc) + (size_t)((ly * 32 + ci) * 9)) << 12)
                      + (size_t)h0 * 576;
        const uint* src = (const uint*)(Wb + base);
        for (int j = tid; j < 1152; j += 256) sW[j] = src[j];
        __syncthreads();

        const ushort_t* sw = (const ushort_t*)sW;
        const float* xp = x + (((size_t)n * CN + ci) << 12);
        int sbase = r * 576 + w * 9;
        #pragma unroll
        for (int kk = 0; kk < 9; kk++) {
            int kh = kk / 3;
            int kw = kk - kh * 3;
            float wv = __uint_as_float((uint)sw[sbase + kk] << 16);
            int y  = h + kh - 1;
            int xw = w + kw - 1;
            float xv = ((unsigned)y < 64u && (unsigned)xw < 64u)
                       ? xp[(y << 6) + xw] : 0.f;
            acc = fmaf(wv, xv, acc);
        }
    }
    out[(((size_t)n * CN + co) << 12) + (h << 6) + w] = acc;
}

extern "C" void kernel_launch(void* const* d_in, const int* in_sizes, int n_in,
                              void* d_out, int out_size, void* d_ws, size_t ws_size,
                              hipStream_t stream) {
    const float* x  = (const float*)d_in[0];
    const float* w1 = (const float*)d_in[1];
    const float* w2 = (const float*)d_in[2];
    float* out = (float*)d_out;
    char* ws = (char*)d_ws;

    float*    hbuf = (float*)ws;                    // 1 MiB
    float*    Bm   = (float*)(ws + (1u << 20));     // 9 MiB
    ushort_t* Wb   = (ushort_t*)(ws + 10485760u);   // up to 144 MiB (bf16)

    // chunk over co so Wb fits ws; chunkC in {32,16,8,4,2}
    const size_t perco = (size_t)NB * KDIM * HW * 2;  // 4.5 MiB per co
    int chunkC = 32;
    while (chunkC > 2 && 10485760ull + (size_t)chunkC * perco > ws_size)
        chunkC >>= 1;

    hipLaunchKernelGGL(conv1_relu, dim3(1024), dim3(256), 0, stream, x, w1, hbuf);
    hipLaunchKernelGGL(im2col_k, dim3((KDIM * PDIM) / 256), dim3(256), 0, stream,
                       hbuf, Bm);

    for (int co0 = 0; co0 < CN; co0 += chunkC) {
        int Mc = chunkC * KDIM;
        hipLaunchKernelGGL(gemm_tanh, dim3(PDIM / 64, Mc / 64), dim3(256), 0, stream,
                           w2 + (size_t)co0 * KDIM * KDIM, Bm, Wb, Mc);
        hipLaunchKernelGGL(apply_kernel, dim3(16, chunkC, NB), dim3(256), 0, stream,
                           x, Wb, out, co0, Mc);
    }
}

// Round 2
// 299.642 us; speedup vs baseline: 2.3512x; 2.3512x over previous
//
#include <hip/hip_runtime.h>

typedef unsigned int uint;
typedef unsigned short ushort_t;

// Problem constants
#define CN 32          // channels
#define HW 4096        // H*W
#define KDIM 288       // C*9
#define PDIM 8192      // N*HW
#define NB 2           // batch

typedef __attribute__((ext_vector_type(8))) short bf16x8;
typedef __attribute__((ext_vector_type(4))) short short4v;
typedef __attribute__((ext_vector_type(4))) float f32x4;

static __device__ __forceinline__ ushort_t f2bf(float f) {
    uint u = __float_as_uint(f);
    uint r = (u + 0x7fffu + ((u >> 16) & 1u)) >> 16;
    return (ushort_t)r;
}

static __device__ __forceinline__ void gl_lds16(const void* g, void* l) {
    __builtin_amdgcn_global_load_lds(
        (const __attribute__((address_space(1))) unsigned int*)g,
        (__attribute__((address_space(3))) unsigned int*)l, 16, 0, 0);
}

// ---------------- conv1 + relu: x (N,32,64,64) -> h ----------------
__global__ __launch_bounds__(256) void conv1_relu(
    const float* __restrict__ x, const float* __restrict__ w1,
    float* __restrict__ hout)
{
    int idx = blockIdx.x * 256 + threadIdx.x;   // N*C*HW = 262144 total
    int w  = idx & 63;
    int hh = (idx >> 6) & 63;
    int c  = (idx >> 12) & 31;
    int n  = idx >> 17;
    const float* wp = w1 + c * KDIM;
    float acc = 0.f;
    for (int ci = 0; ci < CN; ci++) {
        const float* xp = x + (((size_t)n * CN + ci) << 12);
        #pragma unroll
        for (int kh = 0; kh < 3; kh++) {
            int y = hh + kh - 1;
            if ((unsigned)y >= 64u) continue;
            #pragma unroll
            for (int kw = 0; kw < 3; kw++) {
                int xw = w + kw - 1;
                if ((unsigned)xw >= 64u) continue;
                acc = fmaf(xp[(y << 6) + xw], wp[ci * 9 + kh * 3 + kw], acc);
            }
        }
    }
    hout[idx] = fmaxf(acc, 0.f);
}

// ---------------- w2 fp32 -> bf16, layout preserved [m][288] ----------------
__global__ __launch_bounds__(256) void f32_to_bf16_vec(
    const float* __restrict__ in, ushort_t* __restrict__ out, int n4)
{
    int i = blockIdx.x * 256 + threadIdx.x;
    if (i < n4) {
        float4 v = ((const float4*)in)[i];
        alignas(8) ushort_t o[4] = {f2bf(v.x), f2bf(v.y), f2bf(v.z), f2bf(v.w)};
        ((uint2*)out)[i] = *(const uint2*)o;
    }
}

// ---------------- im2col of h, P-MAJOR bf16: Bm[p][k] ----------------
__global__ __launch_bounds__(256) void im2col_bf16(
    const float* __restrict__ h, ushort_t* __restrict__ Bm)
{
    int idx = blockIdx.x * 256 + threadIdx.x;   // PDIM*KDIM
    int k = idx % KDIM;
    int p = idx / KDIM;
    int n  = p >> 12;
    int sp = p & 4095;
    int hh = sp >> 6;
    int w  = sp & 63;
    int ci = k / 9;
    int kk = k - ci * 9;
    int kh = kk / 3;
    int kw = kk - kh * 3;
    int y  = hh + kh - 1;
    int xw = w + kw - 1;
    float v = 0.f;
    if ((unsigned)y < 64u && (unsigned)xw < 64u)
        v = h[(((size_t)n * CN + ci) << 12) + (y << 6) + xw];
    Bm[idx] = f2bf(v);
}

// ---------------- MFMA GEMM (bf16) + tanh + bf16 store ----------------
// A: [Mc][288] bf16 (chunk-offset), B: [8192][288] bf16 (p-major)
// Wb[(n*Mc + m)*4096 + sp] = bf16(tanh(sum_k A[m][k]*B[p][k]))
__global__ __launch_bounds__(256) void gemm_tanh_mfma(
    const ushort_t* __restrict__ A, const ushort_t* __restrict__ B,
    ushort_t* __restrict__ Wb, int Mc)
{
    __shared__ ushort_t AL[128 * 32];   // [m][k] linear, 8 KiB
    __shared__ ushort_t BL[128 * 32];   // [p][k] linear, 8 KiB
    int tid = threadIdx.x;
    int p0 = blockIdx.x * 128;
    int m0 = blockIdx.y * 128;
    int lane = tid & 63, wv = tid >> 6;
    int wm = wv >> 1, wn = wv & 1;      // 2x2 wave grid
    int i16 = lane & 15, kg = lane >> 4;

    f32x4 acc[4][4] = {};

    int rr = tid >> 2;          // 0..63 (row within pass)
    int cc = (tid & 3) * 8;     // k-chunk (8 elements = 16B)

    for (int k0 = 0; k0 < KDIM; k0 += 32) {
        #pragma unroll
        for (int q = 0; q < 2; q++) {
            int r = q * 64 + rr;
            gl_lds16(A + (size_t)(m0 + r) * KDIM + k0 + cc,
                     &AL[q * 2048 + wv * 512]);
            gl_lds16(B + (size_t)(p0 + r) * KDIM + k0 + cc,
                     &BL[q * 2048 + wv * 512]);
        }
        __syncthreads();

        bf16x8 af[4], bfr[4];
        #pragma unroll
        for (int mf = 0; mf < 4; mf++) {
            const ushort_t* ap = &AL[(wm * 64 + mf * 16 + i16) * 32 + kg * 4];
            short4v lo = *(const short4v*)ap;
            short4v hi = *(const short4v*)(ap + 16);
            af[mf] = __builtin_shufflevector(lo, hi, 0, 1, 2, 3, 4, 5, 6, 7);
        }
        #pragma unroll
        for (int nf = 0; nf < 4; nf++) {
            const ushort_t* bp = &BL[(wn * 64 + nf * 16 + i16) * 32 + kg * 4];
            short4v lo = *(const short4v*)bp;
            short4v hi = *(const short4v*)(bp + 16);
            bfr[nf] = __builtin_shufflevector(lo, hi, 0, 1, 2, 3, 4, 5, 6, 7);
        }
        #pragma unroll
        for (int mf = 0; mf < 4; mf++)
            #pragma unroll
            for (int nf = 0; nf < 4; nf++)
                acc[mf][nf] = __builtin_amdgcn_mfma_f32_16x16x32_bf16(
                    af[mf], bfr[nf], acc[mf][nf], 0, 0, 0);
        __syncthreads();
    }

    // epilogue: tanh + bf16 scatter (2B stores, 16-lane contiguous)
    int n   = p0 >> 12;               // 128 | 4096 -> uniform n per block
    int sp0 = p0 & 4095;
    #pragma unroll
    for (int mf = 0; mf < 4; mf++) {
        #pragma unroll
        for (int nf = 0; nf < 4; nf++) {
            int p = sp0 + wn * 64 + nf * 16 + i16;
            #pragma unroll
            for (int r = 0; r < 4; r++) {
                int m = m0 + wm * 64 + mf * 16 + kg * 4 + r;
                float v = tanhf(acc[mf][nf][r]);
                Wb[((size_t)(n * Mc + m) << 12) + p] = f2bf(v);
            }
        }
    }
}

// ---------------- apply: out[n,co,h,w] = sum_{ci,kk} W * x ----------------
// reference reshape semantics: weight(co,ci,h,w,kk) lives at flat offset
// 9*sp + kk within the (co,ci) 9-channel block of channel-major Wb.
__global__ __launch_bounds__(256) void apply_kernel(
    const float* __restrict__ x, const ushort_t* __restrict__ Wb,
    float* __restrict__ out, int co0, int Mc)
{
    __shared__ uint sW[1152];      // 4 rows * 576 bf16 = 2304 bf16
    int tid = threadIdx.x;
    int ly  = blockIdx.y;          // local co
    int co  = co0 + ly;
    int n   = blockIdx.z;
    int h0  = blockIdx.x * 4;
    int r = tid >> 6;
    int w = tid & 63;
    int h = h0 + r;
    float acc = 0.f;

    for (int ci = 0; ci < CN; ci++) {
        __syncthreads();
        size_t base = (((size_t)(n * Mc) + (size_t)((ly * 32 + ci) * 9)) << 12)
                      + (size_t)h0 * 576;
        const uint* src = (const uint*)(Wb + base);
        for (int j = tid; j < 1152; j += 256) sW[j] = src[j];
        __syncthreads();

        const ushort_t* sw = (const ushort_t*)sW;
        const float* xp = x + (((size_t)n * CN + ci) << 12);
        int sbase = r * 576 + w * 9;
        #pragma unroll
        for (int kk = 0; kk < 9; kk++) {
            int kh = kk / 3;
            int kw = kk - kh * 3;
            float wv = __uint_as_float((uint)sw[sbase + kk] << 16);
            int y  = h + kh - 1;
            int xw = w + kw - 1;
            float xv = ((unsigned)y < 64u && (unsigned)xw < 64u)
                       ? xp[(y << 6) + xw] : 0.f;
            acc = fmaf(wv, xv, acc);
        }
    }
    out[(((size_t)n * CN + co) << 12) + (h << 6) + w] = acc;
}

extern "C" void kernel_launch(void* const* d_in, const int* in_sizes, int n_in,
                              void* d_out, int out_size, void* d_ws, size_t ws_size,
                              hipStream_t stream) {
    const float* x  = (const float*)d_in[0];
    const float* w1 = (const float*)d_in[1];
    const float* w2 = (const float*)d_in[2];
    float* out = (float*)d_out;
    char* ws = (char*)d_ws;

    float*    hbuf  = (float*)ws;                       // 1 MiB
    ushort_t* Bm_bf = (ushort_t*)(ws + 1048576u);       // 8192*288*2 = 4718592 B
    ushort_t* A_bf  = (ushort_t*)(ws + 5767168u);       // 9216*288*2 = 5308416 B
    ushort_t* Wb    = (ushort_t*)(ws + 11075584u);      // up to ~151 MiB

    // chunk over co so Wb fits ws; chunkC in {32,16,8,4} (Mc must be /128)
    const size_t perco = (size_t)NB * KDIM * HW * 2;    // 4.5 MiB per co
    int chunkC = 32;
    while (chunkC > 4 && 11075584ull + (size_t)chunkC * perco > ws_size)
        chunkC >>= 1;

    hipLaunchKernelGGL(conv1_relu, dim3(1024), dim3(256), 0, stream, x, w1, hbuf);
    hipLaunchKernelGGL(f32_to_bf16_vec, dim3(2592), dim3(256), 0, stream,
                       w2, A_bf, (9216 * KDIM) / 4);
    hipLaunchKernelGGL(im2col_bf16, dim3((PDIM * KDIM) / 256), dim3(256), 0, stream,
                       hbuf, Bm_bf);

    for (int co0 = 0; co0 < CN; co0 += chunkC) {
        int Mc = chunkC * KDIM;
        hipLaunchKernelGGL(gemm_tanh_mfma, dim3(PDIM / 128, Mc / 128), dim3(256),
                           0, stream, A_bf + (size_t)co0 * KDIM * KDIM, Bm_bf, Wb, Mc);
        hipLaunchKernelGGL(apply_kernel, dim3(16, chunkC, NB), dim3(256), 0, stream,
                           x, Wb, out, co0, Mc);
    }
}

// Round 4
// 193.190 us; speedup vs baseline: 3.6468x; 1.5510x over previous
//
#include <hip/hip_runtime.h>

typedef unsigned int uint;
typedef unsigned short ushort_t;

// Problem constants
#define CN 32          // channels
#define HW 4096        // H*W
#define KDIM 288       // C*9
#define PDIM 8192      // N*HW
#define NB 2           // batch

typedef __attribute__((ext_vector_type(8))) short bf16x8;
typedef __attribute__((ext_vector_type(4))) float f32x4;

static __device__ __forceinline__ ushort_t f2bf(float f) {
    uint u = __float_as_uint(f);
    uint r = (u + 0x7fffu + ((u >> 16) & 1u)) >> 16;
    return (ushort_t)r;
}

static __device__ __forceinline__ void gl_lds16(const void* g, void* l) {
    __builtin_amdgcn_global_load_lds(
        (const __attribute__((address_space(1))) unsigned int*)g,
        (__attribute__((address_space(3))) unsigned int*)l, 16, 0, 0);
}

static __device__ __forceinline__ float fast_tanh(float v) {
    // tanh(v) = 1 - 2/(1+e^{2v}); exact at +-inf, ~1e-7 rel err
    float e = __expf(2.0f * v);
    return 1.0f - 2.0f / (e + 1.0f);
}

// k-permutation within each 32-k group: chunk slot s (16B, 8 elems) holds
// logical k = {g*32 + 4s..4s+3, g*32 + 16+4s..16+4s+3}. A lane's whole MFMA
// fragment (k = kg*4+j, 16+kg*4+j) is then ONE contiguous 16B LDS chunk.

// ---------------- conv1 + relu: x (N,32,64,64) -> h ----------------
__global__ __launch_bounds__(256) void conv1_relu(
    const float* __restrict__ x, const float* __restrict__ w1,
    float* __restrict__ hout)
{
    int idx = blockIdx.x * 256 + threadIdx.x;   // N*C*HW = 262144 total
    int w  = idx & 63;
    int hh = (idx >> 6) & 63;
    int c  = (idx >> 12) & 31;
    int n  = idx >> 17;
    const float* wp = w1 + c * KDIM;
    float acc = 0.f;
    for (int ci = 0; ci < CN; ci++) {
        const float* xp = x + (((size_t)n * CN + ci) << 12);
        #pragma unroll
        for (int kh = 0; kh < 3; kh++) {
            int y = hh + kh - 1;
            if ((unsigned)y >= 64u) continue;
            #pragma unroll
            for (int kw = 0; kw < 3; kw++) {
                int xw = w + kw - 1;
                if ((unsigned)xw >= 64u) continue;
                acc = fmaf(xp[(y << 6) + xw], wp[ci * 9 + kh * 3 + kw], acc);
            }
        }
    }
    hout[idx] = fmaxf(acc, 0.f);
}

// ---------------- w2 fp32 -> bf16, k-PERMUTED rows [9216][288] ----------------
__global__ __launch_bounds__(256) void w2_to_bf16_perm(
    const float* __restrict__ in, ushort_t* __restrict__ out)
{
    int idx = blockIdx.x * 256 + threadIdx.x;   // chunk id, 9216*36 total
    int row = idx / 36;                          // 36 chunks per 288-k row
    int cw  = idx - row * 36;
    int g = cw >> 2, s = cw & 3;
    const float* base = in + (size_t)row * KDIM + g * 32;
    float4 lo = *(const float4*)(base + s * 4);
    float4 hi = *(const float4*)(base + 16 + s * 4);
    alignas(16) ushort_t o[8] = {f2bf(lo.x), f2bf(lo.y), f2bf(lo.z), f2bf(lo.w),
                                 f2bf(hi.x), f2bf(hi.y), f2bf(hi.z), f2bf(hi.w)};
    *(uint4*)(out + (size_t)idx * 8) = *(const uint4*)o;
}

// ---------------- im2col of h, P-MAJOR k-PERMUTED bf16: Bm[p][kperm] ----------------
__global__ __launch_bounds__(256) void im2col_bf16_perm(
    const float* __restrict__ h, ushort_t* __restrict__ Bm)
{
    int idx = blockIdx.x * 256 + threadIdx.x;   // PDIM*KDIM
    int kp = idx % KDIM;
    int p  = idx / KDIM;
    // invert permutation: logical k for permuted position kp
    int pos = kp & 31, s = pos >> 3, j = pos & 7;
    int ko = (j < 4) ? (s * 4 + j) : (16 + s * 4 + j - 4);
    int k  = (kp & ~31) + ko;
    int n  = p >> 12;
    int sp = p & 4095;
    int hh = sp >> 6;
    int w  = sp & 63;
    int ci = k / 9;
    int kk = k - ci * 9;
    int kh = kk / 3;
    int kw = kk - kh * 3;
    int y  = hh + kh - 1;
    int xw = w + kw - 1;
    float v = 0.f;
    if ((unsigned)y < 64u && (unsigned)xw < 64u)
        v = h[(((size_t)n * CN + ci) << 12) + (y << 6) + xw];
    Bm[idx] = f2bf(v);
}

// ---------------- MFMA GEMM (bf16) + tanh + bf16 store ----------------
// A: [Mc][288] bf16 k-permuted (chunk-offset), B: [8192][288] bf16 p-major
// k-permuted. Wb[(n*Mc+m)*4096+sp] = bf16(tanh(sum_k A[m][k]*B[p][k])).
// LDS XOR swizzle: phys 16B-slot = logical_slot ^ ((row>>1)&3); applied on
// the pre-swizzled global SOURCE at staging + on ds_read addresses.
__global__ __launch_bounds__(256) void gemm_tanh_mfma(
    const ushort_t* __restrict__ A, const ushort_t* __restrict__ B,
    ushort_t* __restrict__ Wb, int Mc)
{
    __shared__ ushort_t AL[128 * 32];   // 8 KiB
    __shared__ ushort_t BL[128 * 32];   // 8 KiB
    int tid = threadIdx.x;
    int p0 = blockIdx.x * 128;
    int m0 = blockIdx.y * 128;
    int lane = tid & 63, wv = tid >> 6;
    int wm = wv >> 1, wn = wv & 1;      // 2x2 wave grid
    int i16 = lane & 15, kg = lane >> 4;

    f32x4 acc[4][4] = {};

    for (int k0 = 0; k0 < KDIM; k0 += 32) {
        #pragma unroll
        for (int q = 0; q < 2; q++) {
            int c = q * 256 + tid;             // chunk 0..511: 128 rows x 4 slots
            int row = c >> 2;
            int k8 = (((c & 3) ^ ((c >> 3) & 3)) << 3);   // pre-swizzled source
            gl_lds16(A + (size_t)(m0 + row) * KDIM + k0 + k8,
                     &AL[q * 2048 + wv * 512]);
            gl_lds16(B + (size_t)(p0 + row) * KDIM + k0 + k8,
                     &BL[q * 2048 + wv * 512]);
        }
        __syncthreads();

        bf16x8 af[4], bfr[4];
        #pragma unroll
        for (int mf = 0; mf < 4; mf++) {
            int row = wm * 64 + mf * 16 + i16;
            af[mf] = *(const bf16x8*)&AL[row * 32 + ((kg ^ ((row >> 1) & 3)) << 3)];
        }
        #pragma unroll
        for (int nf = 0; nf < 4; nf++) {
            int row = wn * 64 + nf * 16 + i16;
            bfr[nf] = *(const bf16x8*)&BL[row * 32 + ((kg ^ ((row >> 1) & 3)) << 3)];
        }
        #pragma unroll
        for (int mf = 0; mf < 4; mf++)
            #pragma unroll
            for (int nf = 0; nf < 4; nf++)
                acc[mf][nf] = __builtin_amdgcn_mfma_f32_16x16x32_bf16(
                    af[mf], bfr[nf], acc[mf][nf], 0, 0, 0);
        __syncthreads();
    }

    // epilogue: tanh + bf16 store (R2-proven mapping)
    int n   = p0 >> 12;               // 128 | 4096 -> uniform n per block
    int sp0 = p0 & 4095;
    #pragma unroll
    for (int mf = 0; mf < 4; mf++) {
        #pragma unroll
        for (int nf = 0; nf < 4; nf++) {
            int p = sp0 + wn * 64 + nf * 16 + i16;
            #pragma unroll
            for (int r = 0; r < 4; r++) {
                int m = m0 + wm * 64 + mf * 16 + kg * 4 + r;
                Wb[((size_t)(n * Mc + m) << 12) + p] = f2bf(fast_tanh(acc[mf][nf][r]));
            }
        }
    }
}

// ---------------- apply: out[n,co,h,w] = sum_{ci,kk} W * x ----------------
// reshape semantics: weight(co,ci,h,w,kk) = Wb block (co,ci) [9 channels x HW
// contiguous] at flat offset t = h*576 + w*9 + kk. (R2-proven.)
__global__ __launch_bounds__(256) void apply_kernel(
    const float* __restrict__ x, const ushort_t* __restrict__ Wb,
    float* __restrict__ out, int co0, int Mc)
{
    __shared__ uint sW[1152];      // 4 rows * 576 bf16 = 2304 bf16
    int tid = threadIdx.x;
    int ly  = blockIdx.y;          // local co
    int co  = co0 + ly;
    int n   = blockIdx.z;
    int h0  = blockIdx.x * 4;
    int r = tid >> 6;
    int w = tid & 63;
    int h = h0 + r;
    float acc = 0.f;

    for (int ci = 0; ci < CN; ci++) {
        __syncthreads();
        size_t base = (((size_t)(n * Mc) + (size_t)((ly * 32 + ci) * 9)) << 12)
                      + (size_t)h0 * 576;
        const uint* src = (const uint*)(Wb + base);
        for (int j = tid; j < 1152; j += 256) sW[j] = src[j];
        __syncthreads();

        const ushort_t* sw = (const ushort_t*)sW;
        const float* xp = x + (((size_t)n * CN + ci) << 12);
        int sbase = r * 576 + w * 9;
        #pragma unroll
        for (int kk = 0; kk < 9; kk++) {
            int kh = kk / 3;
            int kw = kk - kh * 3;
            float wv = __uint_as_float((uint)sw[sbase + kk] << 16);
            int y  = h + kh - 1;
            int xw = w + kw - 1;
            float xv = ((unsigned)y < 64u && (unsigned)xw < 64u)
                       ? xp[(y << 6) + xw] : 0.f;
            acc = fmaf(wv, xv, acc);
        }
    }
    out[(((size_t)n * CN + co) << 12) + (h << 6) + w] = acc;
}

extern "C" void kernel_launch(void* const* d_in, const int* in_sizes, int n_in,
                              void* d_out, int out_size, void* d_ws, size_t ws_size,
                              hipStream_t stream) {
    const float* x  = (const float*)d_in[0];
    const float* w1 = (const float*)d_in[1];
    const float* w2 = (const float*)d_in[2];
    float* out = (float*)d_out;
    char* ws = (char*)d_ws;

    float*    hbuf  = (float*)ws;                       // 1 MiB
    ushort_t* Bm_bf = (ushort_t*)(ws + 1048576u);       // 8192*288*2 = 4718592 B
    ushort_t* A_bf  = (ushort_t*)(ws + 5767168u);       // 9216*288*2 = 5308416 B
    ushort_t* Wb    = (ushort_t*)(ws + 11075584u);      // up to ~151 MiB (bf16)

    // chunk over co so Wb fits ws; chunkC in {32,16,8,4}
    const size_t perco = (size_t)NB * KDIM * HW * 2;    // 4.5 MiB per co
    int chunkC = 32;
    while (chunkC > 4 && 11075584ull + (size_t)chunkC * perco > ws_size)
        chunkC >>= 1;

    hipLaunchKernelGGL(conv1_relu, dim3(1024), dim3(256), 0, stream, x, w1, hbuf);
    hipLaunchKernelGGL(w2_to_bf16_perm, dim3(1296), dim3(256), 0, stream, w2, A_bf);
    hipLaunchKernelGGL(im2col_bf16_perm, dim3((PDIM * KDIM) / 256), dim3(256), 0,
                       stream, hbuf, Bm_bf);

    for (int co0 = 0; co0 < CN; co0 += chunkC) {
        int Mc = chunkC * KDIM;
        hipLaunchKernelGGL(gemm_tanh_mfma, dim3(PDIM / 128, Mc / 128), dim3(256),
                           0, stream, A_bf + (size_t)co0 * KDIM * KDIM, Bm_bf, Wb, Mc);
        hipLaunchKernelGGL(apply_kernel, dim3(16, chunkC, NB), dim3(256), 0, stream,
                           x, Wb, out, co0, Mc);
    }
}

// Round 5
// 152.288 us; speedup vs baseline: 4.6263x; 1.2686x over previous
//
#include <hip/hip_runtime.h>

typedef unsigned int uint;
typedef unsigned short ushort_t;

// Problem constants
#define CN 32          // channels
#define HW 4096        // H*W
#define KDIM 288       // C*9
#define PDIM 8192      // N*HW
#define NB 2           // batch

typedef __attribute__((ext_vector_type(8))) short bf16x8;
typedef __attribute__((ext_vector_type(4))) float f32x4;

static __device__ __forceinline__ ushort_t f2bf(float f) {
    uint u = __float_as_uint(f);
    uint r = (u + 0x7fffu + ((u >> 16) & 1u)) >> 16;
    return (ushort_t)r;
}

static __device__ __forceinline__ void gl_lds16(const void* g, void* l) {
    __builtin_amdgcn_global_load_lds(
        (const __attribute__((address_space(1))) unsigned int*)g,
        (__attribute__((address_space(3))) unsigned int*)l, 16, 0, 0);
}

static __device__ __forceinline__ float fast_tanh(float v) {
    // tanh(v) = 1 - 2/(1+e^{2v}); exact at +-inf, ~1e-7 rel err
    float e = __expf(2.0f * v);
    return 1.0f - 2.0f / (e + 1.0f);
}

// k-permutation within each 32-k group: chunk slot s (16B, 8 elems) holds
// logical k = {g*32 + 4s..4s+3, g*32 + 16+4s..16+4s+3}. A lane's whole MFMA
// fragment (k = kg*4+j, 16+kg*4+j) is then ONE contiguous 16B LDS chunk.

// ---------------- out zeroing (fused kernel accumulates via atomics) --------
__global__ __launch_bounds__(256) void zero_out(float4* __restrict__ out) {
    out[blockIdx.x * 256 + threadIdx.x] = make_float4(0.f, 0.f, 0.f, 0.f);
}

// ---------------- conv1 + relu: x (N,32,64,64) -> h ----------------
__global__ __launch_bounds__(256) void conv1_relu(
    const float* __restrict__ x, const float* __restrict__ w1,
    float* __restrict__ hout)
{
    int idx = blockIdx.x * 256 + threadIdx.x;   // N*C*HW = 262144 total
    int w  = idx & 63;
    int hh = (idx >> 6) & 63;
    int c  = (idx >> 12) & 31;
    int n  = idx >> 17;
    const float* wp = w1 + c * KDIM;
    float acc = 0.f;
    for (int ci = 0; ci < CN; ci++) {
        const float* xp = x + (((size_t)n * CN + ci) << 12);
        #pragma unroll
        for (int kh = 0; kh < 3; kh++) {
            int y = hh + kh - 1;
            if ((unsigned)y >= 64u) continue;
            #pragma unroll
            for (int kw = 0; kw < 3; kw++) {
                int xw = w + kw - 1;
                if ((unsigned)xw >= 64u) continue;
                acc = fmaf(xp[(y << 6) + xw], wp[ci * 9 + kh * 3 + kw], acc);
            }
        }
    }
    hout[idx] = fmaxf(acc, 0.f);
}

// ---------------- w2 fp32 -> bf16, k-PERMUTED rows [9216][288] ----------------
__global__ __launch_bounds__(256) void w2_to_bf16_perm(
    const float* __restrict__ in, ushort_t* __restrict__ out)
{
    int idx = blockIdx.x * 256 + threadIdx.x;   // chunk id, 9216*36 total
    int row = idx / 36;                          // 36 chunks per 288-k row
    int cw  = idx - row * 36;
    int g = cw >> 2, s = cw & 3;
    const float* base = in + (size_t)row * KDIM + g * 32;
    float4 lo = *(const float4*)(base + s * 4);
    float4 hi = *(const float4*)(base + 16 + s * 4);
    alignas(16) ushort_t o[8] = {f2bf(lo.x), f2bf(lo.y), f2bf(lo.z), f2bf(lo.w),
                                 f2bf(hi.x), f2bf(hi.y), f2bf(hi.z), f2bf(hi.w)};
    *(uint4*)(out + (size_t)idx * 8) = *(const uint4*)o;
}

// ---------------- im2col of h, P-MAJOR k-PERMUTED bf16: Bm[p][kperm] ----------------
__global__ __launch_bounds__(256) void im2col_bf16_perm(
    const float* __restrict__ h, ushort_t* __restrict__ Bm)
{
    int idx = blockIdx.x * 256 + threadIdx.x;   // PDIM*KDIM
    int kp = idx % KDIM;
    int p  = idx / KDIM;
    // invert permutation: logical k for permuted position kp
    int pos = kp & 31, s = pos >> 3, j = pos & 7;
    int ko = (j < 4) ? (s * 4 + j) : (16 + s * 4 + j - 4);
    int k  = (kp & ~31) + ko;
    int n  = p >> 12;
    int sp = p & 4095;
    int hh = sp >> 6;
    int w  = sp & 63;
    int ci = k / 9;
    int kk = k - ci * 9;
    int kh = kk / 3;
    int kw = kk - kh * 3;
    int y  = hh + kh - 1;
    int xw = w + kw - 1;
    float v = 0.f;
    if ((unsigned)y < 64u && (unsigned)xw < 64u)
        v = h[(((size_t)n * CN + ci) << 12) + (y << 6) + xw];
    Bm[idx] = f2bf(v);
}

// ---------------- fused: MFMA GEMM + tanh + non-uniform apply ----------------
// Semantics (verified against the passing R4 apply_kernel):
//   W(co,ci,t) = tanh(rst[(co*32+ci)*9 + (t>>12), n*4096 + (t&4095)]),
//   out[n,co,sp] = sum_{ci,kk} W(co,ci, t=sp*9+kk) * x[n,ci,nbr(sp,kk)].
// Block = (tw, cog, n): t-window [T0, T0+128), T0 = tw*128. Since 128|4096 and
// T0+127 never crosses a 4096 multiple, c8 = t>>12 is block-constant and the
// B columns are the contiguous q-window [T0&4095, +128). A-rows are the
// gathered set (cog*4+g)*288 + ci*9 + c8 (M = 128 = 4 co x 32 ci).
// GEMM structure (tiles, swizzle, frag reads) copied from the R4-proven gemm.
__global__ __launch_bounds__(256) void fused_gemm_apply(
    const ushort_t* __restrict__ A, const ushort_t* __restrict__ B,
    const float* __restrict__ x, float* __restrict__ out)
{
    __shared__ ushort_t AL[128 * 32];   // 8 KiB
    __shared__ ushort_t BL[128 * 32];   // 8 KiB
    __shared__ float vred[4][128];      // per-(g, t_local) ci-summed values

    int tid = threadIdx.x;
    int tw  = blockIdx.x;               // 0..287
    int cog = blockIdx.y;               // 0..7
    int n   = blockIdx.z;               // 0..1
    int lane = tid & 63, wv = tid >> 6;
    int wm = wv >> 1, wn = wv & 1;      // 2x2 wave grid: wm->m, wn->t
    int i16 = lane & 15, kg = lane >> 4;

    int T0 = tw * 128;
    int c8 = T0 >> 12;                  // block-constant rst sub-channel
    int q0 = T0 & 4095;                 // contiguous B column window start

    f32x4 acc[4][4] = {};

    for (int k0 = 0; k0 < KDIM; k0 += 32) {
        #pragma unroll
        for (int q = 0; q < 2; q++) {
            int c = q * 256 + tid;             // chunk 0..511: 128 rows x 4 slots
            int row = c >> 2;
            int k8 = (((c & 3) ^ ((c >> 3) & 3)) << 3);   // pre-swizzled source
            int arow = (cog * 4 + (row >> 5)) * KDIM + (row & 31) * 9 + c8;
            gl_lds16(A + (size_t)arow * KDIM + k0 + k8, &AL[q * 2048 + wv * 512]);
            int brow = (n << 12) + q0 + row;
            gl_lds16(B + (size_t)brow * KDIM + k0 + k8, &BL[q * 2048 + wv * 512]);
        }
        __syncthreads();

        bf16x8 af[4], bfr[4];
        #pragma unroll
        for (int mf = 0; mf < 4; mf++) {
            int row = wm * 64 + mf * 16 + i16;
            af[mf] = *(const bf16x8*)&AL[row * 32 + ((kg ^ ((row >> 1) & 3)) << 3)];
        }
        #pragma unroll
        for (int nf = 0; nf < 4; nf++) {
            int row = wn * 64 + nf * 16 + i16;
            bfr[nf] = *(const bf16x8*)&BL[row * 32 + ((kg ^ ((row >> 1) & 3)) << 3)];
        }
        #pragma unroll
        for (int mf = 0; mf < 4; mf++)
            #pragma unroll
            for (int nf = 0; nf < 4; nf++)
                acc[mf][nf] = __builtin_amdgcn_mfma_f32_16x16x32_bf16(
                    af[mf], bfr[nf], acc[mf][nf], 0, 0, 0);
        __syncthreads();
    }

    // ---- epilogue: tanh, x-weighted, reduce over ci (m) then kk (t) ----
    // D layout: m_local = wm*64 + mf*16 + kg*4 + r, t_local = wn*64 + nf*16 + i16
    // ci = (mf*16 + kg*4 + r) & 31 -> mf even: ci = kg*4+r; mf odd: +16
    // g  = 2*wm + (mf>>1)
    const float* xn = x + (((size_t)n * CN) << 12);
    #pragma unroll
    for (int nf = 0; nf < 4; nf++) {
        int t  = T0 + wn * 64 + nf * 16 + i16;
        uint sp = ((uint)t * 58255u) >> 19;       // t/9, exact for t < 74898
        int kk = t - (int)sp * 9;
        int kh = (kk * 11) >> 5;                  // kk/3
        int kw = kk - kh * 3;
        int y  = (int)(sp >> 6) + kh - 1;
        int xw = (int)(sp & 63) + kw - 1;
        bool ok = ((unsigned)y < 64u) && ((unsigned)xw < 64u);
        int poff = (y << 6) + xw;
        float xa[4], xb[4];
        #pragma unroll
        for (int r = 0; r < 4; r++) {
            int cia = kg * 4 + r;
            xa[r] = ok ? xn[((size_t)cia << 12) + poff] : 0.f;
            xb[r] = ok ? xn[((size_t)(cia + 16) << 12) + poff] : 0.f;
        }
        float s0 = 0.f, s1 = 0.f;
        #pragma unroll
        for (int r = 0; r < 4; r++) {
            s0 = fmaf(fast_tanh(acc[0][nf][r]), xa[r], s0);
            s0 = fmaf(fast_tanh(acc[1][nf][r]), xb[r], s0);
            s1 = fmaf(fast_tanh(acc[2][nf][r]), xa[r], s1);
            s1 = fmaf(fast_tanh(acc[3][nf][r]), xb[r], s1);
        }
        // sum the 4 kg groups (lanes l, l^16, l^32, l^48 share t) -> all 32 ci
        s0 += __shfl_xor(s0, 16); s0 += __shfl_xor(s0, 32);
        s1 += __shfl_xor(s1, 16); s1 += __shfl_xor(s1, 32);
        if (kg == 0) {
            vred[2 * wm + 0][wn * 64 + nf * 16 + i16] = s0;
            vred[2 * wm + 1][wn * 64 + nf * 16 + i16] = s1;
        }
    }
    __syncthreads();

    // ---- fold 9 t's per pixel, atomicAdd (2-way only on window boundaries) ----
    if (tid < 64) {
        int g  = tid >> 4, bi = tid & 15;
        uint spA = ((uint)T0 * 58255u) >> 19;
        int sp = (int)spA + bi;
        int lo = sp * 9;     if (lo < T0) lo = T0;
        int hi = sp * 9 + 9; if (hi > T0 + 128) hi = T0 + 128;
        if (lo < hi) {
            float s = 0.f;
            for (int t = lo; t < hi; t++) s += vred[g][t - T0];
            atomicAdd(&out[(((size_t)n * CN + cog * 4 + g) << 12) + sp], s);
        }
    }
}

extern "C" void kernel_launch(void* const* d_in, const int* in_sizes, int n_in,
                              void* d_out, int out_size, void* d_ws, size_t ws_size,
                              hipStream_t stream) {
    const float* x  = (const float*)d_in[0];
    const float* w1 = (const float*)d_in[1];
    const float* w2 = (const float*)d_in[2];
    float* out = (float*)d_out;
    char* ws = (char*)d_ws;

    float*    hbuf  = (float*)ws;                       // 1 MiB
    ushort_t* Bm_bf = (ushort_t*)(ws + 1048576u);       // 8192*288*2 = 4718592 B
    ushort_t* A_bf  = (ushort_t*)(ws + 5767168u);       // 9216*288*2 = 5308416 B

    hipLaunchKernelGGL(zero_out, dim3(256), dim3(256), 0, stream, (float4*)out);
    hipLaunchKernelGGL(conv1_relu, dim3(1024), dim3(256), 0, stream, x, w1, hbuf);
    hipLaunchKernelGGL(w2_to_bf16_perm, dim3(1296), dim3(256), 0, stream, w2, A_bf);
    hipLaunchKernelGGL(im2col_bf16_perm, dim3((PDIM * KDIM) / 256), dim3(256), 0,
                       stream, hbuf, Bm_bf);
    hipLaunchKernelGGL(fused_gemm_apply, dim3(288, 8, 2), dim3(256), 0, stream,
                       A_bf, Bm_bf, x, out);
}